// Round 2
// baseline (1997.773 us; speedup 1.0000x reference)
//
#include <hip/hip_runtime.h>
#include <hip/hip_bf16.h>

typedef __hip_bfloat16 bf16;
typedef __attribute__((ext_vector_type(8))) short bf16x8;
typedef __attribute__((ext_vector_type(4))) float f32x4;

#define HQ 24
#define DH 128
#define SQQ 2560
#define SKK 4608
#define NIN 3072
#define NRANK 1024

__device__ __forceinline__ f32x4 mfma16(bf16x8 a, bf16x8 b, f32x4 c) {
  return __builtin_amdgcn_mfma_f32_16x16x32_bf16(a, b, c, 0, 0, 0);
}

__device__ __forceinline__ void gll16(const void* g, void* l) {
  __builtin_amdgcn_global_load_lds((const __attribute__((address_space(1))) void*)g,
                                   (__attribute__((address_space(3))) void*)l, 16, 0, 0);
}

// ---------------- elementwise f32 -> bf16 ----------------
__global__ void f2b_kernel(const float* __restrict__ x, bf16* __restrict__ y) {
  size_t i = ((size_t)blockIdx.x * blockDim.x + threadIdx.x) * 4;
  float4 v = *reinterpret_cast<const float4*>(x + i);
  y[i + 0] = __float2bfloat16(v.x);
  y[i + 1] = __float2bfloat16(v.y);
  y[i + 2] = __float2bfloat16(v.z);
  y[i + 3] = __float2bfloat16(v.w);
}

// ---------------- W[K][N] f32 -> Wt[N][K] bf16 (transpose+convert) ----------------
__global__ void wtrans_kernel(const float* __restrict__ W, bf16* __restrict__ Wt, int K, int N) {
  __shared__ float t[32][33];
  int n0 = blockIdx.x * 32, k0 = blockIdx.y * 32;
  int tx = threadIdx.x, ty = threadIdx.y;
#pragma unroll
  for (int r = 0; r < 4; r++)
    t[ty + r * 8][tx] = W[(size_t)(k0 + ty + r * 8) * N + n0 + tx];
  __syncthreads();
#pragma unroll
  for (int r = 0; r < 4; r++)
    Wt[(size_t)(n0 + ty + r * 8) * K + k0 + tx] = __float2bfloat16(t[tx][ty + r * 8]);
}

// ---------------- GEMM: C[M][N] = A[M][K] @ Bt[N][K]^T (+bias) ----------------
// m97 structure: 128x128 tile, BK=32, 4 waves, global_load_lds(16B), 2-barrier loop.
template <int CMODE>  // 0: f32 C no bias; 1: f32 C + bias; 2: bf16 C no bias
__global__ __launch_bounds__(256, 2) void gemm_kernel(
    const bf16* __restrict__ A, const bf16* __restrict__ Bt,
    float* __restrict__ Cf, bf16* __restrict__ Cb,
    const float* __restrict__ bias, int M, int N, int K) {
  __shared__ bf16 Alds[128 * 32];
  __shared__ bf16 Blds[128 * 32];
  int tid = threadIdx.x;
  int lane = tid & 63, w = tid >> 6;
  int wr = w >> 1, wc = w & 1;
  int bm = blockIdx.x * 128, bn = blockIdx.y * 128;
  int l15 = lane & 15, lg = lane >> 4;

  // staging: each wave fills rows [w*32, w*32+32) of both tiles, 2 gll calls each
  int srow = w * 32 + (lane >> 2);
  int scol = (lane & 3) * 8;
  const bf16* ag = A + (size_t)(bm + srow) * K + scol;
  const bf16* bg = Bt + (size_t)(bn + srow) * K + scol;
  bf16* al0 = &Alds[(w * 32) * 32];
  bf16* al1 = &Alds[(w * 32 + 16) * 32];
  bf16* bl0 = &Blds[(w * 32) * 32];
  bf16* bl1 = &Blds[(w * 32 + 16) * 32];

  f32x4 acc[4][4] = {};

  for (int kt = 0; kt < K; kt += 32) {
    gll16(ag + kt, al0);
    gll16(ag + (size_t)16 * K + kt, al1);
    gll16(bg + kt, bl0);
    gll16(bg + (size_t)16 * K + kt, bl1);
    __syncthreads();
    bf16x8 af[4], bfr[4];
#pragma unroll
    for (int i = 0; i < 4; i++)
      af[i] = *reinterpret_cast<const bf16x8*>(&Alds[(wr * 64 + i * 16 + l15) * 32 + lg * 8]);
#pragma unroll
    for (int j = 0; j < 4; j++)
      bfr[j] = *reinterpret_cast<const bf16x8*>(&Blds[(wc * 64 + j * 16 + l15) * 32 + lg * 8]);
#pragma unroll
    for (int i = 0; i < 4; i++)
#pragma unroll
      for (int j = 0; j < 4; j++)
        acc[i][j] = mfma16(af[i], bfr[j], acc[i][j]);
    __syncthreads();
  }

  int crow0 = bm + wr * 64 + lg * 4;
  int ccol0 = bn + wc * 64 + l15;
#pragma unroll
  for (int j = 0; j < 4; j++) {
    int col = ccol0 + j * 16;
    float bv = (CMODE == 1) ? bias[col] : 0.0f;
#pragma unroll
    for (int i = 0; i < 4; i++) {
#pragma unroll
      for (int r = 0; r < 4; r++) {
        int row = crow0 + i * 16 + r;
        float v = acc[i][j][r] + bv;
        if (CMODE == 2) Cb[(size_t)row * N + col] = __float2bfloat16(v);
        else            Cf[(size_t)row * N + col] = v;
      }
    }
  }
}

// ---------------- build q: [txt|img] -> RMS(+w) -> RoPE -> q_bf16[h][p][d] ----------------
__global__ void build_q_kernel(const float* __restrict__ rawImg, const float* __restrict__ rawTxt,
                               const float* __restrict__ nqw, const float* __restrict__ naqw,
                               const float* __restrict__ rcos, const float* __restrict__ rsin,
                               bf16* __restrict__ qb) {
  int p = blockIdx.x, h = blockIdx.y, t = threadIdx.x;
  const float* src;
  const float* nw;
  if (p < 512) { src = rawTxt + (size_t)p * NIN; nw = naqw; }
  else         { src = rawImg + (size_t)(p - 512) * NIN; nw = nqw; }
  int d0 = 2 * t, d1 = 2 * t + 1;
  float x0 = src[h * DH + d0], x1 = src[h * DH + d1];
  float ss = x0 * x0 + x1 * x1;
#pragma unroll
  for (int m = 1; m < 64; m <<= 1) ss += __shfl_xor(ss, m);
  float rr = rsqrtf(ss * (1.0f / 128.0f) + 1e-6f);
  float y0 = x0 * rr * nw[d0], y1 = x1 * rr * nw[d1];
  float c0 = rcos[(size_t)p * DH + d0], c1 = rcos[(size_t)p * DH + d1];
  float s0 = rsin[(size_t)p * DH + d0], s1 = rsin[(size_t)p * DH + d1];
  float o0 = y0 * c0 - y1 * s0;
  float o1 = y1 * c1 + y0 * s1;
  size_t base = ((size_t)h * SQQ + p) * DH;
  qb[base + d0] = __float2bfloat16(o0);
  qb[base + d1] = __float2bfloat16(o1);
}

// ---------------- build k: [txt|img|ref] -> RMS -> RoPE -> k_bf16[h][p][d] ----------------
__global__ void build_k_kernel(const float* __restrict__ rawImg, const float* __restrict__ rawTxt,
                               const float* __restrict__ rawRef,
                               const float* __restrict__ nkw, const float* __restrict__ nakw,
                               const float* __restrict__ rcos, const float* __restrict__ rsin,
                               const float* __restrict__ ccos, const float* __restrict__ csin,
                               bf16* __restrict__ kb) {
  int p = blockIdx.x, h = blockIdx.y, t = threadIdx.x;
  const float* src;
  const float* nw;
  const float* cs;
  const float* sn;
  float eps;
  if (p < 512)       { src = rawTxt + (size_t)p * NIN;           nw = nakw;    eps = 1e-6f; cs = rcos + (size_t)p * DH;           sn = rsin + (size_t)p * DH; }
  else if (p < 2560) { src = rawImg + (size_t)(p - 512) * NIN;   nw = nkw;     eps = 1e-6f; cs = rcos + (size_t)p * DH;           sn = rsin + (size_t)p * DH; }
  else               { src = rawRef + (size_t)(p - 2560) * NIN;  nw = nullptr; eps = 1e-5f; cs = ccos + (size_t)(p - 2560) * DH;  sn = csin + (size_t)(p - 2560) * DH; }
  int d0 = 2 * t, d1 = 2 * t + 1;
  float x0 = src[h * DH + d0], x1 = src[h * DH + d1];
  float ss = x0 * x0 + x1 * x1;
#pragma unroll
  for (int m = 1; m < 64; m <<= 1) ss += __shfl_xor(ss, m);
  float rr = rsqrtf(ss * (1.0f / 128.0f) + eps);
  float w0 = nw ? nw[d0] : 1.0f, w1 = nw ? nw[d1] : 1.0f;
  float y0 = x0 * rr * w0, y1 = x1 * rr * w1;
  float o0 = y0 * cs[d0] - y1 * sn[d0];
  float o1 = y1 * cs[d1] + y0 * sn[d1];
  size_t base = ((size_t)h * SKK + p) * DH;
  kb[base + d0] = __float2bfloat16(o0);
  kb[base + d1] = __float2bfloat16(o1);
}

// ---------------- v transpose: src f32 [S][3072] -> vt bf16 [24][128][4608] ----------------
__global__ void vt_build_kernel(const float* __restrict__ src, bf16* __restrict__ vt, int p0g) {
  __shared__ float t[32][33];
  int h = blockIdx.y >> 2;
  int d0 = (blockIdx.y & 3) * 32;
  int p0 = blockIdx.x * 32;
  int tx = threadIdx.x, ty = threadIdx.y;
#pragma unroll
  for (int r = 0; r < 4; r++) {
    int p = p0 + ty + r * 8;
    t[ty + r * 8][tx] = src[(size_t)p * NIN + h * DH + d0 + tx];
  }
  __syncthreads();
#pragma unroll
  for (int r = 0; r < 4; r++) {
    int d = d0 + ty + r * 8;
    vt[((size_t)h * DH + d) * SKK + p0g + p0 + tx] = __float2bfloat16(t[tx][ty + r * 8]);
  }
}

// ---------------- flash attention ----------------
// grid 480 x 256 threads; wave = 32 q rows of one head; 32-key chunks, online softmax.
__global__ __launch_bounds__(256, 2) void attn_kernel(
    const bf16* __restrict__ q,   // [24][2560][128]
    const bf16* __restrict__ k,   // [24][4608][128]
    const bf16* __restrict__ vt,  // [24][128][4608]
    bf16* __restrict__ o)         // [2560][3072]
{
  __shared__ bf16 plds_all[4][32 * 32];
  int lane = threadIdx.x & 63;
  int wv = threadIdx.x >> 6;
  int wid = blockIdx.x * 4 + wv;
  int h = wid / 80;
  int qbase = (wid % 80) * 32;
  bf16* plds = plds_all[wv];
  int l15 = lane & 15, lg = lane >> 4;
  const float scale = 0.08838834764831845f;

  bf16x8 qf[2][4];
  const bf16* qg = q + ((size_t)h * SQQ + qbase + l15) * DH + lg * 8;
#pragma unroll
  for (int rb = 0; rb < 2; rb++)
#pragma unroll
    for (int kk = 0; kk < 4; kk++)
      qf[rb][kk] = *reinterpret_cast<const bf16x8*>(qg + rb * 16 * DH + kk * 32);

  f32x4 acc[2][8] = {};
  float mstate[2][4], lstate[2][4];
#pragma unroll
  for (int rb = 0; rb < 2; rb++)
#pragma unroll
    for (int r = 0; r < 4; r++) { mstate[rb][r] = -1e30f; lstate[rb][r] = 0.0f; }

  const bf16* kg = k + ((size_t)h * SKK + l15) * DH + lg * 8;
  const bf16* vg = vt + ((size_t)h * DH + l15) * SKK + lg * 8;

  for (int kc = 0; kc < SKK; kc += 32) {
    f32x4 s[2][2] = {};
#pragma unroll
    for (int kk = 0; kk < 4; kk++) {
      bf16x8 kf0 = *reinterpret_cast<const bf16x8*>(kg + (size_t)kc * DH + kk * 32);
      bf16x8 kf1 = *reinterpret_cast<const bf16x8*>(kg + (size_t)(kc + 16) * DH + kk * 32);
      s[0][0] = mfma16(qf[0][kk], kf0, s[0][0]);
      s[0][1] = mfma16(qf[0][kk], kf1, s[0][1]);
      s[1][0] = mfma16(qf[1][kk], kf0, s[1][0]);
      s[1][1] = mfma16(qf[1][kk], kf1, s[1][1]);
    }
#pragma unroll
    for (int rb = 0; rb < 2; rb++) {
#pragma unroll
      for (int r = 0; r < 4; r++) {
        float a = s[rb][0][r] * scale;
        float b = s[rb][1][r] * scale;
        float mx = fmaxf(a, b);
        mx = fmaxf(mx, __shfl_xor(mx, 1));
        mx = fmaxf(mx, __shfl_xor(mx, 2));
        mx = fmaxf(mx, __shfl_xor(mx, 4));
        mx = fmaxf(mx, __shfl_xor(mx, 8));
        float mold = mstate[rb][r];
        float mnew = fmaxf(mold, mx);
        float corr = __expf(mold - mnew);
        mstate[rb][r] = mnew;
        float e0 = __expf(a - mnew);
        float e1 = __expf(b - mnew);
        float rs = e0 + e1;
        rs += __shfl_xor(rs, 1);
        rs += __shfl_xor(rs, 2);
        rs += __shfl_xor(rs, 4);
        rs += __shfl_xor(rs, 8);
        lstate[rb][r] = lstate[rb][r] * corr + rs;
#pragma unroll
        for (int nf = 0; nf < 8; nf++) acc[rb][nf][r] *= corr;
        int qr = rb * 16 + lg * 4 + r;
        plds[qr * 32 + l15] = __float2bfloat16(e0);
        plds[qr * 32 + 16 + l15] = __float2bfloat16(e1);
      }
    }
    __syncthreads();
    bf16x8 pa0 = *reinterpret_cast<const bf16x8*>(&plds[l15 * 32 + lg * 8]);
    bf16x8 pa1 = *reinterpret_cast<const bf16x8*>(&plds[(16 + l15) * 32 + lg * 8]);
#pragma unroll
    for (int nf = 0; nf < 8; nf++) {
      bf16x8 vf = *reinterpret_cast<const bf16x8*>(vg + (size_t)(nf * 16) * SKK + kc);
      acc[0][nf] = mfma16(pa0, vf, acc[0][nf]);
      acc[1][nf] = mfma16(pa1, vf, acc[1][nf]);
    }
    __syncthreads();
  }

#pragma unroll
  for (int rb = 0; rb < 2; rb++) {
#pragma unroll
    for (int nf = 0; nf < 8; nf++) {
#pragma unroll
      for (int r = 0; r < 4; r++) {
        int p = qbase + rb * 16 + lg * 4 + r;
        int col = h * DH + nf * 16 + l15;
        float v = acc[rb][nf][r] / lstate[rb][r];
        o[(size_t)p * NIN + col] = __float2bfloat16(v);
      }
    }
  }
}

// ---------------- host ----------------
extern "C" void kernel_launch(void* const* d_in, const int* in_sizes, int n_in,
                              void* d_out, int out_size, void* d_ws, size_t ws_size,
                              hipStream_t stream) {
  const float* hs   = (const float*)d_in[0];
  const float* enc  = (const float*)d_in[1];
  const float* ref  = (const float*)d_in[2];
  const float* rcos = (const float*)d_in[3];
  const float* rsin = (const float*)d_in[4];
  const float* ccos = (const float*)d_in[5];
  const float* csin = (const float*)d_in[6];
  const float* Wq   = (const float*)d_in[7];  const float* bq   = (const float*)d_in[8];
  const float* Wk   = (const float*)d_in[9];  const float* bk   = (const float*)d_in[10];
  const float* Wv   = (const float*)d_in[11]; const float* bv   = (const float*)d_in[12];
  const float* Waq  = (const float*)d_in[13]; const float* baq  = (const float*)d_in[14];
  const float* Wak  = (const float*)d_in[15]; const float* bak  = (const float*)d_in[16];
  const float* Wav  = (const float*)d_in[17]; const float* bav  = (const float*)d_in[18];
  const float* Wout = (const float*)d_in[19]; const float* bout = (const float*)d_in[20];
  const float* Wadd = (const float*)d_in[21]; const float* badd = (const float*)d_in[22];
  const float* nqw  = (const float*)d_in[23]; const float* nkw  = (const float*)d_in[24];
  const float* naqw = (const float*)d_in[25]; const float* nakw = (const float*)d_in[26];
  const float* lkd  = (const float*)d_in[27]; const float* lku  = (const float*)d_in[28];
  const float* lvd  = (const float*)d_in[29]; const float* lvu  = (const float*)d_in[30];

  char* ws = (char*)d_ws;
  size_t off = 0;
  bf16* act_h = (bf16*)(ws + off); off += (size_t)2048 * 3072 * 2;
  bf16* act_e = (bf16*)(ws + off); off += (size_t)512 * 3072 * 2;
  bf16* act_r = (bf16*)(ws + off); off += (size_t)2048 * 3072 * 2;
  bf16* qbuf  = (bf16*)(ws + off); off += (size_t)24 * 2560 * 128 * 2;
  bf16* kbuf  = (bf16*)(ws + off); off += (size_t)24 * 4608 * 128 * 2;
  bf16* vtbuf = (bf16*)(ws + off); off += (size_t)24 * 128 * 4608 * 2;
  bf16* obuf  = (bf16*)(ws + off); off += (size_t)2560 * 3072 * 2;
  bf16* wt    = (bf16*)(ws + off); off += (size_t)3072 * 3072 * 2;
  float* rawA = (float*)(ws + off); off += (size_t)2048 * 3072 * 4;
  float* rawB = (float*)(ws + off); off += (size_t)512 * 3072 * 4;
  float* rawC = (float*)(ws + off); off += (size_t)2048 * 3072 * 4;
  bf16* mid   = (bf16*)(ws + off);  off += (size_t)2048 * 1024 * 2;

  dim3 tb32(32, 8);
  auto wtr = [&](const float* W, int K, int N) {
    wtrans_kernel<<<dim3(N / 32, K / 32), tb32, 0, stream>>>(W, wt, K, N);
  };
  auto gemm_b = [&](const bf16* A, float* C, const float* bias, int M, int N, int K) {
    gemm_kernel<1><<<dim3(M / 128, N / 128), 256, 0, stream>>>(A, wt, C, nullptr, bias, M, N, K);
  };
  auto gemm_f = [&](const bf16* A, float* C, int M, int N, int K) {
    gemm_kernel<0><<<dim3(M / 128, N / 128), 256, 0, stream>>>(A, wt, C, nullptr, nullptr, M, N, K);
  };
  auto gemm_h = [&](const bf16* A, bf16* C, int M, int N, int K) {
    gemm_kernel<2><<<dim3(M / 128, N / 128), 256, 0, stream>>>(A, wt, nullptr, C, nullptr, M, N, K);
  };

  // 1. activations -> bf16
  f2b_kernel<<<6144, 256, 0, stream>>>(hs, act_h);
  f2b_kernel<<<1536, 256, 0, stream>>>(enc, act_e);
  f2b_kernel<<<6144, 256, 0, stream>>>(ref, act_r);

  // 2. Q path
  wtr(Wq, 3072, 3072);  gemm_b(act_h, rawA, bq, 2048, 3072, 3072);
  wtr(Waq, 3072, 3072); gemm_b(act_e, rawB, baq, 512, 3072, 3072);
  build_q_kernel<<<dim3(2560, 24), 64, 0, stream>>>(rawA, rawB, nqw, naqw, rcos, rsin, qbuf);

  // 3. K path
  wtr(Wk, 3072, 3072);  gemm_b(act_h, rawA, bk, 2048, 3072, 3072);
  wtr(Wak, 3072, 3072); gemm_b(act_e, rawB, bak, 512, 3072, 3072);
  wtr(lkd, 3072, 1024); gemm_h(act_r, mid, 2048, 1024, 3072);
  wtr(lku, 1024, 3072); gemm_f(mid, rawC, 2048, 3072, 1024);
  build_k_kernel<<<dim3(4608, 24), 64, 0, stream>>>(rawA, rawB, rawC, nkw, nakw,
                                                    rcos, rsin, ccos, csin, kbuf);

  // 4. V path
  wtr(Wv, 3072, 3072);  gemm_b(act_h, rawA, bv, 2048, 3072, 3072);
  wtr(Wav, 3072, 3072); gemm_b(act_e, rawB, bav, 512, 3072, 3072);
  wtr(lvd, 3072, 1024); gemm_h(act_r, mid, 2048, 1024, 3072);
  wtr(lvu, 1024, 3072); gemm_f(mid, rawC, 2048, 3072, 1024);
  vt_build_kernel<<<dim3(64, 96), tb32, 0, stream>>>(rawA, vtbuf, 512);
  vt_build_kernel<<<dim3(16, 96), tb32, 0, stream>>>(rawB, vtbuf, 0);
  vt_build_kernel<<<dim3(64, 96), tb32, 0, stream>>>(rawC, vtbuf, 2560);

  // 5. attention
  attn_kernel<<<480, 256, 0, stream>>>(qbuf, kbuf, vtbuf, obuf);

  // 6. output projections -> d_out (hid_out [2048][3072] then enc_out [512][3072])
  float* out_hid = (float*)d_out;
  float* out_enc = out_hid + (size_t)2048 * 3072;
  wtr(Wout, 3072, 3072); gemm_b(obuf + (size_t)512 * 3072, out_hid, bout, 2048, 3072, 3072);
  wtr(Wadd, 3072, 3072); gemm_b(obuf, out_enc, badd, 512, 3072, 3072);
}